// Round 7
// baseline (3602.782 us; speedup 1.0000x reference)
//
#include <hip/hip_runtime.h>

typedef __bf16 bf16;
typedef short s16x8 __attribute__((ext_vector_type(8)));
typedef float f32x4 __attribute__((ext_vector_type(4)));

#define MFMA16(a, b, c) __builtin_amdgcn_mfma_f32_16x16x32_bf16((a), (b), (c), 0, 0, 0)
#define NROW 187   // cand rows per batch: 63 init + 2 per iter (62 iters)

__device__ __forceinline__ float sigf(float x) { return 1.0f / (1.0f + expf(-x)); }
__device__ __forceinline__ s16x8 ld8(const bf16* p) { return *(const s16x8*)p; }

// ---------------- device-global workspace (fp32 in / fp32 out: R3-verified) --
__device__ bf16  g_xhi[64 * 64 * 512], g_xlo[64 * 64 * 512];
__device__ bf16  g_wwhi[1024 * 512], g_wwlo[1024 * 512];
__device__ bf16  g_wchi[2560 * 1024], g_wclo[2560 * 1024];
__device__ float g_c[64 * 64 * 512];          // leaf c state fp32
__device__ bf16  g_hhi[64 * 64 * 512];        // leaf h hi
__device__ bf16  g_hlo[64 * 64 * 512];        // leaf h lo
// candidate rows: NEVER overwritten within a call (monotonic alloc) -> no WAR
__device__ float g_candh[(size_t)64 * NROW * 512];
__device__ float g_candc[(size_t)64 * NROW * 512];
__device__ bf16  g_candhhi[(size_t)64 * NROW * 512];
__device__ bf16  g_candhlo[(size_t)64 * NROW * 512];
__device__ float g_spinit[64 * 63 * 32];
__device__ float g_spart[2 * 128 * 32];       // [parity][rg*16+row][fg]
__device__ int   g_bar[63 * 128];             // [it][rg*16] arrive counters

// ---------------- prep: fp32 -> bf16 hi/lo split ---------------------------
__global__ __launch_bounds__(256) void k_prep_split(const float* __restrict__ src,
                                                    int n, bf16* __restrict__ hi,
                                                    bf16* __restrict__ lo) {
    for (int i = blockIdx.x * 256 + threadIdx.x; i < n; i += gridDim.x * 256) {
        float v = src[i];
        bf16 h = (bf16)v;
        hi[i] = h;
        lo[i] = (bf16)(v - (float)h);
    }
}

// ---------------------------------------------------------------------------
// K0: leaf projection (M=4096, N=1024, K=512), 3-pass hi/lo MFMA.
// Layouts (m89/m120): A[m=l15][k=quad*8+j], B[k][n=l15], D row=quad*4+reg.
// ---------------------------------------------------------------------------
__global__ __launch_bounds__(64) void k_leaf(const float* __restrict__ b_word) {
    int cg = blockIdx.x, rg = blockIdx.y;
    int lane = threadIdx.x, l15 = lane & 15, quad = lane >> 4;
    const bf16* axh = g_xhi + (size_t)(rg * 16 + l15) * 512;
    const bf16* axl = g_xlo + (size_t)(rg * 16 + l15) * 512;
    const bf16* bwh = g_wwhi + (size_t)(cg * 64 + l15) * 512;
    const bf16* bwl = g_wwlo + (size_t)(cg * 64 + l15) * 512;
    f32x4 acc[4] = {};
    for (int kc = 0; kc < 16; ++kc) {
        int k = kc * 32 + quad * 8;
        s16x8 aH = ld8(axh + k), aL = ld8(axl + k);
#pragma unroll
        for (int t = 0; t < 4; ++t) {
            s16x8 bH = ld8(bwh + (size_t)t * 16 * 512 + k);
            s16x8 bL = ld8(bwl + (size_t)t * 16 * 512 + k);
            acc[t] = MFMA16(aH, bH, acc[t]);
            acc[t] = MFMA16(aH, bL, acc[t]);
            acc[t] = MFMA16(aL, bH, acc[t]);
        }
    }
#pragma unroll
    for (int t = 0; t < 4; ++t) {
        int col = cg * 64 + t * 16 + l15;
        float bw = b_word[col];
#pragma unroll
        for (int r = 0; r < 4; ++r) {
            int m = rg * 16 + quad * 4 + r;
            float v = acc[t][r] + bw;
            if (col < 512) {
                bf16 hi = (bf16)v;
                g_hhi[(size_t)m * 512 + col] = hi;
                g_hlo[(size_t)m * 512 + col] = (bf16)(v - (float)hi);
            } else {
                g_c[(size_t)m * 512 + (col - 512)] = v;
            }
        }
    }
}

// ---------------------------------------------------------------------------
// K1: initial candidates, all pairs (b,j) -> cand rows 0..62 per batch.
// ---------------------------------------------------------------------------
__global__ __launch_bounds__(64) void k_cells_init(const int* __restrict__ length,
                                                   const float* __restrict__ b_comp,
                                                   const float* __restrict__ q) {
    int fg = blockIdx.x;            // 0..31
    int rg = blockIdx.y;            // 0..62
    int lane = threadIdx.x, l15 = lane & 15, quad = lane >> 4;

    const bf16 *ahi[4], *alo[4];
#pragma unroll
    for (int t = 0; t < 4; ++t) {
        int r = rg * 64 + t * 16 + l15;      // pair row 0..4031
        int b = r / 63, j = r - b * 63;
        ahi[t] = g_hhi + (size_t)(b * 64 + j) * 512;
        alo[t] = g_hlo + (size_t)(b * 64 + j) * 512;
    }
    const bf16* wh = g_wchi + (size_t)(fg * 16 + l15) * 1024;
    const bf16* wl = g_wclo + (size_t)(fg * 16 + l15) * 1024;
    f32x4 acc[4][5] = {};
    for (int kc = 0; kc < 32; ++kc) {
        int k = kc * 32 + quad * 8;
        int kk = k & 511;
        size_t sh = (k < 512) ? 0 : 512;     // row j vs j+1 (contiguous rows)
        s16x8 aH[4], aL[4];
#pragma unroll
        for (int t = 0; t < 4; ++t) {
            aH[t] = ld8(ahi[t] + sh + kk);
            aL[t] = ld8(alo[t] + sh + kk);
        }
#pragma unroll
        for (int g = 0; g < 5; ++g) {
            s16x8 bH = ld8(wh + (size_t)g * 512 * 1024 + k);
            s16x8 bL = ld8(wl + (size_t)g * 512 * 1024 + k);
#pragma unroll
            for (int t = 0; t < 4; ++t) {
                acc[t][g] = MFMA16(aH[t], bH, acc[t][g]);
                acc[t][g] = MFMA16(aH[t], bL, acc[t][g]);
                acc[t][g] = MFMA16(aL[t], bH, acc[t][g]);
            }
        }
    }
    int col = fg * 16 + l15;
    float bc[5];
#pragma unroll
    for (int g = 0; g < 5; ++g) bc[g] = b_comp[g * 512 + col];
    float qv = q[col];
#pragma unroll
    for (int t = 0; t < 4; ++t) {
#pragma unroll
        for (int rr = 0; rr < 4; ++rr) {
            int R = rg * 64 + t * 16 + quad * 4 + rr;
            int B_ = R / 63, J = R - B_ * 63;
            bool act = (J <= length[B_] - 2);
            float gi = acc[t][0][rr] + bc[0];
            float fl = acc[t][1][rr] + bc[1];
            float fr = acc[t][2][rr] + bc[2];
            float gu = acc[t][3][rr] + bc[3];
            float go = acc[t][4][rr] + bc[4];
            float cl = g_c[(size_t)(B_ * 64 + J) * 512 + col];
            float cr = g_c[(size_t)(B_ * 64 + J + 1) * 512 + col];
            float cn = cl * sigf(fl + 1.0f) + cr * sigf(fr + 1.0f) + tanhf(gu) * sigf(gi);
            float hn = sigf(go) * tanhf(cn);
            float sp = hn * qv;
#pragma unroll
            for (int off = 1; off < 16; off <<= 1) sp += __shfl_xor(sp, off, 16);
            if (act) {
                size_t o = ((size_t)B_ * NROW + J) * 512 + col;
                g_candh[o] = hn;
                g_candc[o] = cn;
                bf16 hi = (bf16)hn;
                g_candhhi[o] = hi;
                g_candhlo[o] = (bf16)(hn - (float)hi);
                if (l15 == 0) g_spinit[(size_t)R * 32 + fg] = sp;
            }
        }
    }
}

// ---------------------------------------------------------------------------
// K_loop_p: ONE persistent kernel for all 63 iterations.
// grid (32 fg, 8 rg) x 64 thr. Block (fg,rg): features [fg*16,fg*16+16),
// batches [rg*8, rg*8+8). Selection state replicated per block (deterministic
// => identical across fg replicas). Candidate indirection (enc: <64 leaf slot,
// >=64 cand row+64) removes the commit step => one rg-scoped barrier/iter.
// spart parity double-buffered (WAR-safe across the single barrier).
// ---------------------------------------------------------------------------
__global__ __launch_bounds__(64) void k_loop_p(const int* __restrict__ length,
                                               const float* __restrict__ b_comp,
                                               const float* __restrict__ q,
                                               float* __restrict__ out) {
    int fg = blockIdx.x, rg = blockIdx.y;
    int lane = threadIdx.x, l15 = lane & 15, quad = lane >> 4;
    const float sqrt_h = 22.627416997969522f;

    __shared__ int s_next[8][64], s_prev[8][64], s_aliv[8][64];
    __shared__ int s_enc[8][64];    // slot -> current content (slot | 64+candrow)
    __shared__ int s_prow[8][64];   // left-slot -> cand row of its current pair
    __shared__ float s_score[8][64];
    __shared__ int s_np[8][2];
    __shared__ int s_dl[16], s_dr[16], s_dd[16];
    __shared__ int s_len[8];

    // ---- init replica state (reads only prior-dispatch data) ----
    for (int bl = 0; bl < 8; ++bl) {
        int b = rg * 8 + bl;
        int len = length[b];
        if (lane == 0) { s_len[bl] = len; s_np[bl][0] = -1; s_np[bl][1] = -1; }
        s_next[bl][lane] = (lane < len - 1) ? lane + 1 : -1;
        s_prev[bl][lane] = (lane > 0 && lane < len) ? lane - 1 : -1;
        s_aliv[bl][lane] = (lane < len) ? 1 : 0;
        s_enc[bl][lane] = lane;
        s_prow[bl][lane] = lane;
        float sc = -3.0e38f;
        if (lane < 63 && lane <= len - 2) {
            float s = 0.0f;
            for (int f = 0; f < 32; ++f) s += g_spinit[(size_t)(b * 63 + lane) * 32 + f];
            sc = s / sqrt_h;
        }
        s_score[bl][lane] = sc;
    }
    __syncthreads();

    int col = fg * 16 + l15;
    float bc[5];
#pragma unroll
    for (int g = 0; g < 5; ++g) bc[g] = b_comp[g * 512 + col];
    float qv = q[col];
    const bf16* wh = g_wchi + (size_t)col * 1024;
    const bf16* wl = g_wclo + (size_t)col * 1024;

    for (int it = 0; it < 63; ++it) {
        if (it > 0) {
            // rg-scoped barrier: all 32 fg siblings finished GEMM of it-1
            __threadfence();
            if (lane == 0) {
                int* bp = &g_bar[it * 128 + rg * 16];
                atomicAdd(bp, 1);
                while (atomicAdd(bp, 0) < 32) __builtin_amdgcn_s_sleep(2);
            }
            __threadfence();
        }
        // ---------------- selection (replicated, 8 batches) ----------------
        for (int bl = 0; bl < 8; ++bl) {
            int len = s_len[bl];
            int r0 = bl * 2;
            bool active = (it <= len - 2);
            if (!active) {
                if (lane == 0) {
                    s_dl[r0] = 0; s_dr[r0] = 1; s_dd[r0] = -1;
                    s_dl[r0 + 1] = 0; s_dr[r0 + 1] = 1; s_dd[r0 + 1] = -1;
                }
                continue;
            }
            if (it > 0) {
                int s = lane >> 5, f = lane & 31;
                int p = s_np[bl][s];
                float v = (p >= 0)
                    ? g_spart[(((it - 1) & 1) * 128 + rg * 16 + r0 + s) * 32 + f]
                    : 0.0f;
#pragma unroll
                for (int off = 1; off < 32; off <<= 1) v += __shfl_xor(v, off, 32);
                if (f == 0 && p >= 0) s_score[bl][p] = v / sqrt_h;
                __syncthreads();
            }
            // argmax, first-index tie-break
            float val = -3.0e38f;
            int idx = lane;
            if (lane < 63 && s_aliv[bl][lane] && s_next[bl][lane] >= 0)
                val = s_score[bl][lane];
#pragma unroll
            for (int off = 1; off < 64; off <<= 1) {
                float ov = __shfl_xor(val, off, 64);
                int oi = __shfl_xor(idx, off, 64);
                if (ov > val || (ov == val && oi < idx)) { val = ov; idx = oi; }
            }
            int a = idx;
            if (a < 0) a = 0;
            if (a > 62) a = 62;
            if (lane == 0) {
                int bn = s_next[bl][a];
                int nn = (bn >= 0) ? s_next[bl][bn] : -1;
                s_next[bl][a] = nn;
                if (nn >= 0) s_prev[bl][nn] = a;
                if (bn >= 0) s_aliv[bl][bn] = 0;
                s_enc[bl][a] = 64 + s_prow[bl][a];   // slot a := merged cand
                int pL = s_prev[bl][a];
                int pR = (nn >= 0) ? a : -1;
                s_np[bl][0] = pL;
                s_np[bl][1] = pR;
                if (pL >= 0) {
                    s_dl[r0] = s_enc[bl][pL]; s_dr[r0] = s_enc[bl][a];
                    s_dd[r0] = 63 + 2 * it;  s_prow[bl][pL] = 63 + 2 * it;
                } else { s_dl[r0] = 0; s_dr[r0] = 1; s_dd[r0] = -1; }
                if (pR >= 0) {
                    s_dl[r0 + 1] = s_enc[bl][a]; s_dr[r0 + 1] = s_enc[bl][nn];
                    s_dd[r0 + 1] = 63 + 2 * it + 1; s_prow[bl][a] = 63 + 2 * it + 1;
                } else { s_dl[r0 + 1] = 0; s_dr[r0 + 1] = 1; s_dd[r0 + 1] = -1; }
            }
        }
        __syncthreads();
        // ---------------- GEMM: 16 pair-rows x 16 cols x 5 gates -----------
        if (it < 62) {
            int b_r = rg * 8 + (l15 >> 1);
            int encl = s_dl[l15], encr = s_dr[l15];
            const bf16* lhi = (encl < 64) ? g_hhi + (size_t)(b_r * 64 + encl) * 512
                : g_candhhi + ((size_t)b_r * NROW + encl - 64) * 512;
            const bf16* llo = (encl < 64) ? g_hlo + (size_t)(b_r * 64 + encl) * 512
                : g_candhlo + ((size_t)b_r * NROW + encl - 64) * 512;
            const bf16* rhi = (encr < 64) ? g_hhi + (size_t)(b_r * 64 + encr) * 512
                : g_candhhi + ((size_t)b_r * NROW + encr - 64) * 512;
            const bf16* rlo = (encr < 64) ? g_hlo + (size_t)(b_r * 64 + encr) * 512
                : g_candhlo + ((size_t)b_r * NROW + encr - 64) * 512;
            f32x4 acc[5] = {};
            for (int kc = 0; kc < 32; ++kc) {
                int k = kc * 32 + quad * 8;
                int kk = k & 511;
                const bf16* ah = (kc < 16) ? lhi : rhi;
                const bf16* al = (kc < 16) ? llo : rlo;
                s16x8 aH = ld8(ah + kk);
                s16x8 aL = ld8(al + kk);
#pragma unroll
                for (int g = 0; g < 5; ++g) {
                    s16x8 bH = ld8(wh + (size_t)g * 512 * 1024 + k);
                    s16x8 bL = ld8(wl + (size_t)g * 512 * 1024 + k);
                    acc[g] = MFMA16(aH, bH, acc[g]);
                    acc[g] = MFMA16(aH, bL, acc[g]);
                    acc[g] = MFMA16(aL, bH, acc[g]);
                }
            }
#pragma unroll
            for (int rr = 0; rr < 4; ++rr) {
                int rowm = quad * 4 + rr;
                int bb = rg * 8 + (rowm >> 1);
                int dest = s_dd[rowm];
                int el = s_dl[rowm], er = s_dr[rowm];
                const float* clp = (el < 64) ? g_c + (size_t)(bb * 64 + el) * 512
                    : g_candc + ((size_t)bb * NROW + el - 64) * 512;
                const float* crp = (er < 64) ? g_c + (size_t)(bb * 64 + er) * 512
                    : g_candc + ((size_t)bb * NROW + er - 64) * 512;
                float gi = acc[0][rr] + bc[0];
                float fl = acc[1][rr] + bc[1];
                float fr = acc[2][rr] + bc[2];
                float gu = acc[3][rr] + bc[3];
                float go = acc[4][rr] + bc[4];
                float cl = clp[col];
                float cr = crp[col];
                float cn = cl * sigf(fl + 1.0f) + cr * sigf(fr + 1.0f) + tanhf(gu) * sigf(gi);
                float hn = sigf(go) * tanhf(cn);
                float sp = hn * qv;
#pragma unroll
                for (int off = 1; off < 16; off <<= 1) sp += __shfl_xor(sp, off, 16);
                if (dest >= 0) {
                    size_t o = ((size_t)bb * NROW + dest) * 512 + col;
                    g_candh[o] = hn;
                    g_candc[o] = cn;
                    bf16 hi = (bf16)hn;
                    g_candhhi[o] = hi;
                    g_candhlo[o] = (bf16)(hn - (float)hi);
                    if (l15 == 0)
                        g_spart[((it & 1) * 128 + rg * 16 + rowm) * 32 + fg] = sp;
                }
            }
        }
        __syncthreads();
    }
    // ---------------- output: root = slot 0 content --------------------------
    for (int ph = 0; ph < 2; ++ph) {
        int bl = quad + 4 * ph;
        int b = rg * 8 + bl;
        int e0 = s_enc[bl][0];
        float hv, cv;
        if (e0 >= 64) {
            size_t o = ((size_t)b * NROW + e0 - 64) * 512 + col;
            hv = g_candh[o];
            cv = g_candc[o];
        } else {   // unreachable for len>=2, defensive
            size_t o = (size_t)(b * 64 + e0) * 512 + col;
            hv = (float)g_hhi[o] + (float)g_hlo[o];
            cv = g_c[o];
        }
        out[(size_t)b * 512 + col] = hv;
        out[(size_t)(64 * 512) + b * 512 + col] = cv;
    }
}

// ---------------------------------------------------------------------------
extern "C" void kernel_launch(void* const* d_in, const int* in_sizes, int n_in,
                              void* d_out, int out_size, void* d_ws, size_t ws_size,
                              hipStream_t stream) {
    const float* x = (const float*)d_in[0];
    const int* length = (const int*)d_in[1];
    const float* w_word = (const float*)d_in[2];
    const float* b_word = (const float*)d_in[3];
    const float* w_comp = (const float*)d_in[4];
    const float* b_comp = (const float*)d_in[5];
    const float* q = (const float*)d_in[6];
    float* out = (float*)d_out;

    bf16 *xhi, *xlo, *wwhi, *wwlo, *wchi, *wclo;
    int* barp;
    hipGetSymbolAddress((void**)&xhi, HIP_SYMBOL(g_xhi));
    hipGetSymbolAddress((void**)&xlo, HIP_SYMBOL(g_xlo));
    hipGetSymbolAddress((void**)&wwhi, HIP_SYMBOL(g_wwhi));
    hipGetSymbolAddress((void**)&wwlo, HIP_SYMBOL(g_wwlo));
    hipGetSymbolAddress((void**)&wchi, HIP_SYMBOL(g_wchi));
    hipGetSymbolAddress((void**)&wclo, HIP_SYMBOL(g_wclo));
    hipGetSymbolAddress((void**)&barp, HIP_SYMBOL(g_bar));

    hipMemsetAsync(barp, 0, 63 * 128 * sizeof(int), stream);
    hipLaunchKernelGGL(k_prep_split, dim3(1024), dim3(256), 0, stream,
                       x, 64 * 64 * 512, xhi, xlo);
    hipLaunchKernelGGL(k_prep_split, dim3(256), dim3(256), 0, stream,
                       w_word, 1024 * 512, wwhi, wwlo);
    hipLaunchKernelGGL(k_prep_split, dim3(1024), dim3(256), 0, stream,
                       w_comp, 2560 * 1024, wchi, wclo);

    hipLaunchKernelGGL(k_leaf, dim3(16, 256), dim3(64), 0, stream, b_word);
    hipLaunchKernelGGL(k_cells_init, dim3(32, 63), dim3(64), 0, stream,
                       length, b_comp, q);

    void* args[] = {(void*)&length, (void*)&b_comp, (void*)&q, (void*)&out};
    hipLaunchCooperativeKernel((void*)k_loop_p, dim3(32, 8), dim3(64), args, 0, stream);
}

// Round 8
// 2966.637 us; speedup vs baseline: 1.2144x; 1.2144x over previous
//
#include <hip/hip_runtime.h>

typedef __bf16 bf16;
typedef short s16x8 __attribute__((ext_vector_type(8)));
typedef float f32x4 __attribute__((ext_vector_type(4)));
typedef unsigned long long u64;

#define MFMA16(a, b, c) __builtin_amdgcn_mfma_f32_16x16x32_bf16((a), (b), (c), 0, 0, 0)
#define NROW 187   // cand rows per batch: 63 init + 2/iter
#define UROW 251   // unified rows: 64 leaf slots + 187 cand rows

__device__ __forceinline__ float sigf(float x) { return 1.0f / (1.0f + expf(-x)); }
__device__ __forceinline__ s16x8 ld8(const bf16* p) { return *(const s16x8*)p; }

__device__ __forceinline__ unsigned packhl(float v) {
    bf16 h = (bf16)v;
    bf16 l = (bf16)(v - (float)h);
    return (unsigned)__builtin_bit_cast(unsigned short, h) |
           ((unsigned)__builtin_bit_cast(unsigned short, l) << 16);
}
__device__ __forceinline__ u64 lda64(const unsigned* p) {
    return __hip_atomic_load((const u64*)p, __ATOMIC_RELAXED, __HIP_MEMORY_SCOPE_AGENT);
}
__device__ __forceinline__ float ldaf(const float* p) {
    return __hip_atomic_load(p, __ATOMIC_RELAXED, __HIP_MEMORY_SCOPE_AGENT);
}
__device__ __forceinline__ void staf(float* p, float v) {
    __hip_atomic_store(p, v, __ATOMIC_RELAXED, __HIP_MEMORY_SCOPE_AGENT);
}
__device__ __forceinline__ void stau(unsigned* p, unsigned v) {
    __hip_atomic_store(p, v, __ATOMIC_RELAXED, __HIP_MEMORY_SCOPE_AGENT);
}

// ---------------- device-global workspace (fp32 in / fp32 out) -------------
__device__ bf16  g_xhi[64 * 64 * 512], g_xlo[64 * 64 * 512];
__device__ bf16  g_wwhi[1024 * 512], g_wwlo[1024 * 512];
__device__ bf16  g_wchi[2560 * 1024], g_wclo[2560 * 1024];
__device__ bf16  g_hhi[64 * 64 * 512];             // leaf h hi (k_cells_init A)
__device__ bf16  g_hlo[64 * 64 * 512];             // leaf h lo
__device__ unsigned g_uhl[(size_t)64 * UROW * 512]; // unified h packed (hi|lo<<16)
__device__ float g_uc[(size_t)64 * UROW * 512];     // unified c fp32
__device__ float g_candh[(size_t)64 * NROW * 512];  // cand h fp32 (self-read only)
__device__ float g_spinit[64 * 63 * 32];
__device__ float g_spart[2 * 128 * 32];             // [parity][rg*16+row][fg]
__device__ int   g_bar[63 * 128];                   // [it][rg*16]

// ---------------- prep: all three fp32 -> bf16 hi/lo splits, one kernel ----
__global__ __launch_bounds__(256) void k_prep(const float* __restrict__ x,
                                              const float* __restrict__ ww,
                                              const float* __restrict__ wc) {
    const int NX = 64 * 64 * 512, NW = 1024 * 512, NC = 2560 * 1024;
    int stride = gridDim.x * 256, i0 = blockIdx.x * 256 + threadIdx.x;
    for (int i = i0; i < NX; i += stride) {
        float v = x[i];
        bf16 h = (bf16)v;
        g_xhi[i] = h;
        g_xlo[i] = (bf16)(v - (float)h);
    }
    for (int i = i0; i < NW; i += stride) {
        float v = ww[i];
        bf16 h = (bf16)v;
        g_wwhi[i] = h;
        g_wwlo[i] = (bf16)(v - (float)h);
    }
    for (int i = i0; i < NC; i += stride) {
        float v = wc[i];
        bf16 h = (bf16)v;
        g_wchi[i] = h;
        g_wclo[i] = (bf16)(v - (float)h);
    }
}

// ---------------------------------------------------------------------------
// K0: leaf projection (M=4096, N=1024, K=512), 3-pass hi/lo MFMA.
// Layouts (m89/m120): A[m=l15][k=quad*8+j], B[k][n=l15], D row=quad*4+reg.
// ---------------------------------------------------------------------------
__global__ __launch_bounds__(64) void k_leaf(const float* __restrict__ b_word) {
    int cg = blockIdx.x, rg = blockIdx.y;
    int lane = threadIdx.x, l15 = lane & 15, quad = lane >> 4;
    const bf16* axh = g_xhi + (size_t)(rg * 16 + l15) * 512;
    const bf16* axl = g_xlo + (size_t)(rg * 16 + l15) * 512;
    const bf16* bwh = g_wwhi + (size_t)(cg * 64 + l15) * 512;
    const bf16* bwl = g_wwlo + (size_t)(cg * 64 + l15) * 512;
    f32x4 acc[4] = {};
    for (int kc = 0; kc < 16; ++kc) {
        int k = kc * 32 + quad * 8;
        s16x8 aH = ld8(axh + k), aL = ld8(axl + k);
#pragma unroll
        for (int t = 0; t < 4; ++t) {
            s16x8 bH = ld8(bwh + (size_t)t * 16 * 512 + k);
            s16x8 bL = ld8(bwl + (size_t)t * 16 * 512 + k);
            acc[t] = MFMA16(aH, bH, acc[t]);
            acc[t] = MFMA16(aH, bL, acc[t]);
            acc[t] = MFMA16(aL, bH, acc[t]);
        }
    }
#pragma unroll
    for (int t = 0; t < 4; ++t) {
        int col = cg * 64 + t * 16 + l15;
        float bw = b_word[col];
#pragma unroll
        for (int r = 0; r < 4; ++r) {
            int m = rg * 16 + quad * 4 + r;
            int bb = m >> 6, sl = m & 63;
            float v = acc[t][r] + bw;
            if (col < 512) {
                bf16 hi = (bf16)v;
                g_hhi[(size_t)m * 512 + col] = hi;
                g_hlo[(size_t)m * 512 + col] = (bf16)(v - (float)hi);
                g_uhl[((size_t)bb * UROW + sl) * 512 + col] = packhl(v);
            } else {
                g_uc[((size_t)bb * UROW + sl) * 512 + (col - 512)] = v;
            }
        }
    }
}

// ---------------------------------------------------------------------------
// K1: initial candidates, all pairs (b,j) -> cand rows 0..62 (enc 64..126).
// ---------------------------------------------------------------------------
__global__ __launch_bounds__(64) void k_cells_init(const int* __restrict__ length,
                                                   const float* __restrict__ b_comp,
                                                   const float* __restrict__ q) {
    int fg = blockIdx.x;            // 0..31
    int rg = blockIdx.y;            // 0..62
    int lane = threadIdx.x, l15 = lane & 15, quad = lane >> 4;

    const bf16 *ahi[4], *alo[4];
#pragma unroll
    for (int t = 0; t < 4; ++t) {
        int r = rg * 64 + t * 16 + l15;      // pair row 0..4031
        int b = r / 63, j = r - b * 63;
        ahi[t] = g_hhi + (size_t)(b * 64 + j) * 512;
        alo[t] = g_hlo + (size_t)(b * 64 + j) * 512;
    }
    const bf16* wh = g_wchi + (size_t)(fg * 16 + l15) * 1024;
    const bf16* wl = g_wclo + (size_t)(fg * 16 + l15) * 1024;
    f32x4 acc[4][5] = {};
    for (int kc = 0; kc < 32; ++kc) {
        int k = kc * 32 + quad * 8;
        int kk = k & 511;
        size_t sh = (k < 512) ? 0 : 512;     // row j vs j+1 (contiguous rows)
        s16x8 aH[4], aL[4];
#pragma unroll
        for (int t = 0; t < 4; ++t) {
            aH[t] = ld8(ahi[t] + sh + kk);
            aL[t] = ld8(alo[t] + sh + kk);
        }
#pragma unroll
        for (int g = 0; g < 5; ++g) {
            s16x8 bH = ld8(wh + (size_t)g * 512 * 1024 + k);
            s16x8 bL = ld8(wl + (size_t)g * 512 * 1024 + k);
#pragma unroll
            for (int t = 0; t < 4; ++t) {
                acc[t][g] = MFMA16(aH[t], bH, acc[t][g]);
                acc[t][g] = MFMA16(aH[t], bL, acc[t][g]);
                acc[t][g] = MFMA16(aL[t], bH, acc[t][g]);
            }
        }
    }
    int col = fg * 16 + l15;
    float bc[5];
#pragma unroll
    for (int g = 0; g < 5; ++g) bc[g] = b_comp[g * 512 + col];
    float qv = q[col];
#pragma unroll
    for (int t = 0; t < 4; ++t) {
#pragma unroll
        for (int rr = 0; rr < 4; ++rr) {
            int R = rg * 64 + t * 16 + quad * 4 + rr;
            int B_ = R / 63, J = R - B_ * 63;
            bool act = (J <= length[B_] - 2);
            float gi = acc[t][0][rr] + bc[0];
            float fl = acc[t][1][rr] + bc[1];
            float fr = acc[t][2][rr] + bc[2];
            float gu = acc[t][3][rr] + bc[3];
            float go = acc[t][4][rr] + bc[4];
            float cl = g_uc[((size_t)B_ * UROW + J) * 512 + col];
            float cr = g_uc[((size_t)B_ * UROW + J + 1) * 512 + col];
            float cn = cl * sigf(fl + 1.0f) + cr * sigf(fr + 1.0f) + tanhf(gu) * sigf(gi);
            float hn = sigf(go) * tanhf(cn);
            float sp = hn * qv;
#pragma unroll
            for (int off = 1; off < 16; off <<= 1) sp += __shfl_xor(sp, off, 16);
            if (act) {
                size_t o = ((size_t)B_ * UROW + 64 + J) * 512 + col;
                g_uhl[o] = packhl(hn);
                g_uc[o] = cn;
                g_candh[((size_t)B_ * NROW + J) * 512 + col] = hn;
                if (l15 == 0) g_spinit[(size_t)R * 32 + fg] = sp;
            }
        }
    }
}

// ---------------------------------------------------------------------------
// K_loop_p: ONE persistent kernel, 63 iterations. grid (32 fg, 8 rg) x 64.
// Cross-block transport: agent-scope relaxed atomics (MALL-coherent, no
// fences -> local L2 stays warm for B-slices). Barrier: waitcnt + relaxed
// fetch_add by arrivers, relaxed LOAD polling (no RMW spin).
// ---------------------------------------------------------------------------
__global__ __launch_bounds__(64) void k_loop_p(const int* __restrict__ length,
                                               const float* __restrict__ b_comp,
                                               const float* __restrict__ q,
                                               float* __restrict__ out) {
    int fg = blockIdx.x, rg = blockIdx.y;
    int lane = threadIdx.x, l15 = lane & 15, quad = lane >> 4;
    const float sqrt_h = 22.627416997969522f;

    __shared__ int s_next[8][64], s_prev[8][64], s_aliv[8][64];
    __shared__ int s_enc[8][64];    // slot -> enc (<64 leaf, 64+candrow)
    __shared__ int s_prow[8][64];   // left-slot -> cand row of its current pair
    __shared__ float s_score[8][64];
    __shared__ int s_np[8][2];
    __shared__ int s_dl[16], s_dr[16], s_dd[16];
    __shared__ int s_len[8];

    for (int bl = 0; bl < 8; ++bl) {
        int b = rg * 8 + bl;
        int len = length[b];
        if (lane == 0) { s_len[bl] = len; s_np[bl][0] = -1; s_np[bl][1] = -1; }
        s_next[bl][lane] = (lane < len - 1) ? lane + 1 : -1;
        s_prev[bl][lane] = (lane > 0 && lane < len) ? lane - 1 : -1;
        s_aliv[bl][lane] = (lane < len) ? 1 : 0;
        s_enc[bl][lane] = lane;
        s_prow[bl][lane] = lane;
        float sc = -3.0e38f;
        if (lane < 63 && lane <= len - 2) {
            float s = 0.0f;
            for (int f = 0; f < 32; ++f) s += g_spinit[(size_t)(b * 63 + lane) * 32 + f];
            sc = s / sqrt_h;
        }
        s_score[bl][lane] = sc;
    }
    __syncthreads();

    int col = fg * 16 + l15;
    float bc[5];
#pragma unroll
    for (int g = 0; g < 5; ++g) bc[g] = b_comp[g * 512 + col];
    float qv = q[col];
    const bf16* wh = g_wchi + (size_t)col * 1024;
    const bf16* wl = g_wclo + (size_t)col * 1024;

    for (int it = 0; it < 63; ++it) {
        if (it > 0) {
            __builtin_amdgcn_s_waitcnt(0);   // all sc1 stores of it-1 complete
            if (lane == 0) {
                int* bp = &g_bar[it * 128 + rg * 16];
                __hip_atomic_fetch_add(bp, 1, __ATOMIC_RELAXED, __HIP_MEMORY_SCOPE_AGENT);
                while (__hip_atomic_load(bp, __ATOMIC_RELAXED, __HIP_MEMORY_SCOPE_AGENT) < 32)
                    __builtin_amdgcn_s_sleep(4);
            }
            __builtin_amdgcn_s_waitcnt(0);
        }
        // ---------------- selection (replicated, 8 batches) ----------------
        for (int bl = 0; bl < 8; ++bl) {
            int len = s_len[bl];
            int r0 = bl * 2;
            bool active = (it <= len - 2);
            if (!active) {
                if (lane == 0) {
                    s_dl[r0] = 0; s_dr[r0] = 1; s_dd[r0] = -1;
                    s_dl[r0 + 1] = 0; s_dr[r0 + 1] = 1; s_dd[r0 + 1] = -1;
                }
                continue;
            }
            if (it > 0) {
                int s = lane >> 5, f = lane & 31;
                int p = s_np[bl][s];
                float v = (p >= 0)
                    ? ldaf(&g_spart[(((it - 1) & 1) * 128 + rg * 16 + r0 + s) * 32 + f])
                    : 0.0f;
#pragma unroll
                for (int off = 1; off < 32; off <<= 1) v += __shfl_xor(v, off, 32);
                if (f == 0 && p >= 0) s_score[bl][p] = v / sqrt_h;
                __syncthreads();
            }
            float val = -3.0e38f;
            int idx = lane;
            if (lane < 63 && s_aliv[bl][lane] && s_next[bl][lane] >= 0)
                val = s_score[bl][lane];
#pragma unroll
            for (int off = 1; off < 64; off <<= 1) {
                float ov = __shfl_xor(val, off, 64);
                int oi = __shfl_xor(idx, off, 64);
                if (ov > val || (ov == val && oi < idx)) { val = ov; idx = oi; }
            }
            int a = idx;
            if (a < 0) a = 0;
            if (a > 62) a = 62;
            if (lane == 0) {
                int bn = s_next[bl][a];
                int nn = (bn >= 0) ? s_next[bl][bn] : -1;
                s_next[bl][a] = nn;
                if (nn >= 0) s_prev[bl][nn] = a;
                if (bn >= 0) s_aliv[bl][bn] = 0;
                s_enc[bl][a] = 64 + s_prow[bl][a];
                int pL = s_prev[bl][a];
                int pR = (nn >= 0) ? a : -1;
                s_np[bl][0] = pL;
                s_np[bl][1] = pR;
                if (pL >= 0) {
                    s_dl[r0] = s_enc[bl][pL]; s_dr[r0] = s_enc[bl][a];
                    s_dd[r0] = 63 + 2 * it;  s_prow[bl][pL] = 63 + 2 * it;
                } else { s_dl[r0] = 0; s_dr[r0] = 1; s_dd[r0] = -1; }
                if (pR >= 0) {
                    s_dl[r0 + 1] = s_enc[bl][a]; s_dr[r0 + 1] = s_enc[bl][nn];
                    s_dd[r0 + 1] = 63 + 2 * it + 1; s_prow[bl][a] = 63 + 2 * it + 1;
                } else { s_dl[r0 + 1] = 0; s_dr[r0 + 1] = 1; s_dd[r0 + 1] = -1; }
            }
        }
        __syncthreads();
        // ---------------- GEMM: 16 pair-rows x 16 cols x 5 gates -----------
        if (it < 62) {
            int b_r = rg * 8 + (l15 >> 1);
            const unsigned* la = g_uhl + ((size_t)b_r * UROW + s_dl[l15]) * 512;
            const unsigned* ra = g_uhl + ((size_t)b_r * UROW + s_dr[l15]) * 512;
            f32x4 acc[5] = {};
            for (int kc = 0; kc < 32; ++kc) {
                int k = kc * 32 + quad * 8;
                int kk = k & 511;
                const unsigned* ap = ((k < 512) ? la : ra) + kk;
                u64 u0 = lda64(ap), u1 = lda64(ap + 2);
                u64 u2 = lda64(ap + 4), u3 = lda64(ap + 6);
                s16x8 aH, aL;
                aH[0] = (short)u0; aL[0] = (short)(u0 >> 16);
                aH[1] = (short)(u0 >> 32); aL[1] = (short)(u0 >> 48);
                aH[2] = (short)u1; aL[2] = (short)(u1 >> 16);
                aH[3] = (short)(u1 >> 32); aL[3] = (short)(u1 >> 48);
                aH[4] = (short)u2; aL[4] = (short)(u2 >> 16);
                aH[5] = (short)(u2 >> 32); aL[5] = (short)(u2 >> 48);
                aH[6] = (short)u3; aL[6] = (short)(u3 >> 16);
                aH[7] = (short)(u3 >> 32); aL[7] = (short)(u3 >> 48);
#pragma unroll
                for (int g = 0; g < 5; ++g) {
                    s16x8 bH = ld8(wh + (size_t)g * 512 * 1024 + k);
                    s16x8 bL = ld8(wl + (size_t)g * 512 * 1024 + k);
                    acc[g] = MFMA16(aH, bH, acc[g]);
                    acc[g] = MFMA16(aH, bL, acc[g]);
                    acc[g] = MFMA16(aL, bH, acc[g]);
                }
            }
#pragma unroll
            for (int rr = 0; rr < 4; ++rr) {
                int rowm = quad * 4 + rr;
                int bb = rg * 8 + (rowm >> 1);
                int dest = s_dd[rowm];
                float cl = ldaf(&g_uc[((size_t)bb * UROW + s_dl[rowm]) * 512 + col]);
                float cr = ldaf(&g_uc[((size_t)bb * UROW + s_dr[rowm]) * 512 + col]);
                float gi = acc[0][rr] + bc[0];
                float fl = acc[1][rr] + bc[1];
                float fr = acc[2][rr] + bc[2];
                float gu = acc[3][rr] + bc[3];
                float go = acc[4][rr] + bc[4];
                float cn = cl * sigf(fl + 1.0f) + cr * sigf(fr + 1.0f) + tanhf(gu) * sigf(gi);
                float hn = sigf(go) * tanhf(cn);
                float sp = hn * qv;
#pragma unroll
                for (int off = 1; off < 16; off <<= 1) sp += __shfl_xor(sp, off, 16);
                if (dest >= 0) {
                    size_t o = ((size_t)bb * UROW + 64 + dest) * 512 + col;
                    stau(&g_uhl[o], packhl(hn));
                    staf(&g_uc[o], cn);
                    g_candh[((size_t)bb * NROW + dest) * 512 + col] = hn;
                    if (l15 == 0)
                        staf(&g_spart[((it & 1) * 128 + rg * 16 + rowm) * 32 + fg], sp);
                }
            }
        }
        __syncthreads();
    }
    // ---------------- output: own cols, own batches ------------------------
    for (int bl = 0; bl < 8; ++bl) {
        if ((lane >> 4) != (bl & 3)) continue;   // spread quads over batches
        int b = rg * 8 + bl;
        int e0 = s_enc[bl][0];                    // root enc (>=64 for len>=2)
        float hv = g_candh[((size_t)b * NROW + e0 - 64) * 512 + col];
        float cv = ldaf(&g_uc[((size_t)b * UROW + e0) * 512 + col]);
        out[(size_t)b * 512 + col] = hv;
        out[(size_t)(64 * 512) + b * 512 + col] = cv;
    }
}

// ---------------------------------------------------------------------------
extern "C" void kernel_launch(void* const* d_in, const int* in_sizes, int n_in,
                              void* d_out, int out_size, void* d_ws, size_t ws_size,
                              hipStream_t stream) {
    const float* x = (const float*)d_in[0];
    const int* length = (const int*)d_in[1];
    const float* w_word = (const float*)d_in[2];
    const float* b_word = (const float*)d_in[3];
    const float* w_comp = (const float*)d_in[4];
    const float* b_comp = (const float*)d_in[5];
    const float* q = (const float*)d_in[6];
    float* out = (float*)d_out;

    int* barp;
    hipGetSymbolAddress((void**)&barp, HIP_SYMBOL(g_bar));
    hipMemsetAsync(barp, 0, 63 * 128 * sizeof(int), stream);

    hipLaunchKernelGGL(k_prep, dim3(2048), dim3(256), 0, stream, x, w_word, w_comp);
    hipLaunchKernelGGL(k_leaf, dim3(16, 256), dim3(64), 0, stream, b_word);
    hipLaunchKernelGGL(k_cells_init, dim3(32, 63), dim3(64), 0, stream,
                       length, b_comp, q);

    void* args[] = {(void*)&length, (void*)&b_comp, (void*)&q, (void*)&out};
    hipLaunchCooperativeKernel((void*)k_loop_p, dim3(32, 8), dim3(64), args, 0, stream);
}

// Round 9
// 2711.072 us; speedup vs baseline: 1.3289x; 1.0943x over previous
//
#include <hip/hip_runtime.h>

typedef __bf16 bf16;
typedef short s16x8 __attribute__((ext_vector_type(8)));
typedef float f32x4 __attribute__((ext_vector_type(4)));

#define MFMA16(a, b, c) __builtin_amdgcn_mfma_f32_16x16x32_bf16((a), (b), (c), 0, 0, 0)
#define NROW 187   // cand rows per batch: 63 init + 2/iter
#define UROW 251   // unified rows: 64 leaf + 187 cand (row index == enc)

__device__ __forceinline__ float sigf(float x) { return 1.0f / (1.0f + expf(-x)); }
__device__ __forceinline__ s16x8 ld8(const bf16* p) { return *(const s16x8*)p; }

// sc1 (agent-scope) STORES: push data to MALL. All consumer loads are PLAIN
// (write-once-per-call + demand-fill + cross-call determinism => never stale).
__device__ __forceinline__ void sta_bf(bf16* p, bf16 v) {
    __hip_atomic_store((unsigned short*)p, __builtin_bit_cast(unsigned short, v),
                       __ATOMIC_RELAXED, __HIP_MEMORY_SCOPE_AGENT);
}
__device__ __forceinline__ void sta_f(float* p, float v) {
    __hip_atomic_store(p, v, __ATOMIC_RELAXED, __HIP_MEMORY_SCOPE_AGENT);
}

// ---------------- device-global workspace (fp32 in / fp32 out) -------------
__device__ bf16  g_xhi[64 * 64 * 512], g_xlo[64 * 64 * 512];
__device__ bf16  g_wwhi[1024 * 512], g_wwlo[1024 * 512];
__device__ bf16  g_wchi[2560 * 1024], g_wclo[2560 * 1024];
__device__ bf16  g_uhhi[(size_t)64 * UROW * 512];   // unified h hi
__device__ bf16  g_uhlo[(size_t)64 * UROW * 512];   // unified h lo
__device__ float g_uc[(size_t)64 * UROW * 512];     // unified c fp32
__device__ float g_candh[(size_t)64 * NROW * 512];  // cand h fp32 (self-read)
__device__ float g_spinit[64 * 63 * 32];
__device__ float g_spart[63 * 128 * 32];            // [it][rg*16+row][fg] write-once
__device__ int   g_bar[63 * 128];                   // [it][rg*16]

// ---------------- prep: all three fp32 -> bf16 hi/lo splits ----------------
__global__ __launch_bounds__(256) void k_prep(const float* __restrict__ x,
                                              const float* __restrict__ ww,
                                              const float* __restrict__ wc) {
    const int NX = 64 * 64 * 512, NW = 1024 * 512, NC = 2560 * 1024;
    int stride = gridDim.x * 256, i0 = blockIdx.x * 256 + threadIdx.x;
    for (int i = i0; i < NX; i += stride) {
        float v = x[i];
        bf16 h = (bf16)v;
        g_xhi[i] = h;
        g_xlo[i] = (bf16)(v - (float)h);
    }
    for (int i = i0; i < NW; i += stride) {
        float v = ww[i];
        bf16 h = (bf16)v;
        g_wwhi[i] = h;
        g_wwlo[i] = (bf16)(v - (float)h);
    }
    for (int i = i0; i < NC; i += stride) {
        float v = wc[i];
        bf16 h = (bf16)v;
        g_wchi[i] = h;
        g_wclo[i] = (bf16)(v - (float)h);
    }
}

// ---------------------------------------------------------------------------
// K0: leaf projection (M=4096, N=1024, K=512), 3-pass hi/lo MFMA.
// Layouts (m89/m120): A[m=l15][k=quad*8+j], B[k][n=l15], D row=quad*4+reg.
// Writes unified rows 0..63 per batch (normal stores; dispatch boundary).
// ---------------------------------------------------------------------------
__global__ __launch_bounds__(64) void k_leaf(const float* __restrict__ b_word) {
    int cg = blockIdx.x, rg = blockIdx.y;
    int lane = threadIdx.x, l15 = lane & 15, quad = lane >> 4;
    const bf16* axh = g_xhi + (size_t)(rg * 16 + l15) * 512;
    const bf16* axl = g_xlo + (size_t)(rg * 16 + l15) * 512;
    const bf16* bwh = g_wwhi + (size_t)(cg * 64 + l15) * 512;
    const bf16* bwl = g_wwlo + (size_t)(cg * 64 + l15) * 512;
    f32x4 acc[4] = {};
    for (int kc = 0; kc < 16; ++kc) {
        int k = kc * 32 + quad * 8;
        s16x8 aH = ld8(axh + k), aL = ld8(axl + k);
#pragma unroll
        for (int t = 0; t < 4; ++t) {
            s16x8 bH = ld8(bwh + (size_t)t * 16 * 512 + k);
            s16x8 bL = ld8(bwl + (size_t)t * 16 * 512 + k);
            acc[t] = MFMA16(aH, bH, acc[t]);
            acc[t] = MFMA16(aH, bL, acc[t]);
            acc[t] = MFMA16(aL, bH, acc[t]);
        }
    }
#pragma unroll
    for (int t = 0; t < 4; ++t) {
        int col = cg * 64 + t * 16 + l15;
        float bw = b_word[col];
#pragma unroll
        for (int r = 0; r < 4; ++r) {
            int m = rg * 16 + quad * 4 + r;
            int bb = m >> 6, sl = m & 63;
            float v = acc[t][r] + bw;
            size_t o = ((size_t)bb * UROW + sl) * 512;
            if (col < 512) {
                bf16 hi = (bf16)v;
                g_uhhi[o + col] = hi;
                g_uhlo[o + col] = (bf16)(v - (float)hi);
            } else {
                g_uc[o + (col - 512)] = v;
            }
        }
    }
}

// ---------------------------------------------------------------------------
// K1: initial candidates, all pairs (b,j) -> unified rows 64..126.
// Leaf rows j, j+1 are contiguous in the unified layout (both < 64).
// ---------------------------------------------------------------------------
__global__ __launch_bounds__(64) void k_cells_init(const int* __restrict__ length,
                                                   const float* __restrict__ b_comp,
                                                   const float* __restrict__ q) {
    int fg = blockIdx.x;            // 0..31
    int rg = blockIdx.y;            // 0..62
    int lane = threadIdx.x, l15 = lane & 15, quad = lane >> 4;

    const bf16 *ahi[4], *alo[4];
#pragma unroll
    for (int t = 0; t < 4; ++t) {
        int r = rg * 64 + t * 16 + l15;      // pair row 0..4031
        int b = r / 63, j = r - b * 63;
        ahi[t] = g_uhhi + ((size_t)b * UROW + j) * 512;
        alo[t] = g_uhlo + ((size_t)b * UROW + j) * 512;
    }
    const bf16* wh = g_wchi + (size_t)(fg * 16 + l15) * 1024;
    const bf16* wl = g_wclo + (size_t)(fg * 16 + l15) * 1024;
    f32x4 acc[4][5] = {};
    for (int kc = 0; kc < 32; ++kc) {
        int k = kc * 32 + quad * 8;
        int kk = k & 511;
        size_t sh = (k < 512) ? 0 : 512;     // row j vs j+1
        s16x8 aH[4], aL[4];
#pragma unroll
        for (int t = 0; t < 4; ++t) {
            aH[t] = ld8(ahi[t] + sh + kk);
            aL[t] = ld8(alo[t] + sh + kk);
        }
#pragma unroll
        for (int g = 0; g < 5; ++g) {
            s16x8 bH = ld8(wh + (size_t)g * 512 * 1024 + k);
            s16x8 bL = ld8(wl + (size_t)g * 512 * 1024 + k);
#pragma unroll
            for (int t = 0; t < 4; ++t) {
                acc[t][g] = MFMA16(aH[t], bH, acc[t][g]);
                acc[t][g] = MFMA16(aH[t], bL, acc[t][g]);
                acc[t][g] = MFMA16(aL[t], bH, acc[t][g]);
            }
        }
    }
    int col = fg * 16 + l15;
    float bc[5];
#pragma unroll
    for (int g = 0; g < 5; ++g) bc[g] = b_comp[g * 512 + col];
    float qv = q[col];
#pragma unroll
    for (int t = 0; t < 4; ++t) {
#pragma unroll
        for (int rr = 0; rr < 4; ++rr) {
            int R = rg * 64 + t * 16 + quad * 4 + rr;
            int B_ = R / 63, J = R - B_ * 63;
            bool act = (J <= length[B_] - 2);
            float gi = acc[t][0][rr] + bc[0];
            float fl = acc[t][1][rr] + bc[1];
            float fr = acc[t][2][rr] + bc[2];
            float gu = acc[t][3][rr] + bc[3];
            float go = acc[t][4][rr] + bc[4];
            float cl = g_uc[((size_t)B_ * UROW + J) * 512 + col];
            float cr = g_uc[((size_t)B_ * UROW + J + 1) * 512 + col];
            float cn = cl * sigf(fl + 1.0f) + cr * sigf(fr + 1.0f) + tanhf(gu) * sigf(gi);
            float hn = sigf(go) * tanhf(cn);
            float sp = hn * qv;
#pragma unroll
            for (int off = 1; off < 16; off <<= 1) sp += __shfl_xor(sp, off, 16);
            if (act) {
                size_t o = ((size_t)B_ * UROW + 64 + J) * 512 + col;
                bf16 hi = (bf16)hn;
                g_uhhi[o] = hi;
                g_uhlo[o] = (bf16)(hn - (float)hi);
                g_uc[o] = cn;
                g_candh[((size_t)B_ * NROW + J) * 512 + col] = hn;
                if (l15 == 0) g_spinit[(size_t)R * 32 + fg] = sp;
            }
        }
    }
}

// ---------------------------------------------------------------------------
// K_loop_p: ONE persistent kernel, 63 iterations. grid (32 fg, 8 rg) x 64.
// Producers: sc1 stores drained by s_waitcnt(0) before the barrier add.
// Consumers: PLAIN loads (pipelineable) — safe per write-once/demand-fill.
// Barrier: relaxed fetch_add by lane0, relaxed load polling.
// ---------------------------------------------------------------------------
__global__ __launch_bounds__(64) void k_loop_p(const int* __restrict__ length,
                                               const float* __restrict__ b_comp,
                                               const float* __restrict__ q,
                                               float* __restrict__ out) {
    int fg = blockIdx.x, rg = blockIdx.y;
    int lane = threadIdx.x, l15 = lane & 15, quad = lane >> 4;
    const float sqrt_h = 22.627416997969522f;

    __shared__ int s_next[8][64], s_prev[8][64], s_aliv[8][64];
    __shared__ int s_enc[8][64];    // slot -> unified row (<64 leaf, >=64 cand)
    __shared__ int s_prow[8][64];   // left-slot -> unified row of current pair
    __shared__ float s_score[8][64];
    __shared__ int s_np[8][2];
    __shared__ int s_dl[16], s_dr[16], s_dd[16];
    __shared__ int s_len[8];

    for (int bl = 0; bl < 8; ++bl) {
        int b = rg * 8 + bl;
        int len = length[b];
        if (lane == 0) { s_len[bl] = len; s_np[bl][0] = -1; s_np[bl][1] = -1; }
        s_next[bl][lane] = (lane < len - 1) ? lane + 1 : -1;
        s_prev[bl][lane] = (lane > 0 && lane < len) ? lane - 1 : -1;
        s_aliv[bl][lane] = (lane < len) ? 1 : 0;
        s_enc[bl][lane] = lane;
        s_prow[bl][lane] = 64 + lane;
        float sc = -3.0e38f;
        if (lane < 63 && lane <= len - 2) {
            float s = 0.0f;
            for (int f = 0; f < 32; ++f) s += g_spinit[(size_t)(b * 63 + lane) * 32 + f];
            sc = s / sqrt_h;
        }
        s_score[bl][lane] = sc;
    }
    __syncthreads();

    int col = fg * 16 + l15;
    float bc[5];
#pragma unroll
    for (int g = 0; g < 5; ++g) bc[g] = b_comp[g * 512 + col];
    float qv = q[col];
    const bf16* wh = g_wchi + (size_t)col * 1024;
    const bf16* wl = g_wclo + (size_t)col * 1024;

    for (int it = 0; it < 63; ++it) {
        float pv[8];
        if (it > 0) {
            __builtin_amdgcn_s_waitcnt(0);   // drain this block's sc1 stores
            if (lane == 0) {
                int* bp = &g_bar[it * 128 + rg * 16];
                __hip_atomic_fetch_add(bp, 1, __ATOMIC_RELAXED, __HIP_MEMORY_SCOPE_AGENT);
                while (__hip_atomic_load(bp, __ATOMIC_RELAXED, __HIP_MEMORY_SCOPE_AGENT) < 32)
                    __builtin_amdgcn_s_sleep(2);
            }
            __atomic_signal_fence(__ATOMIC_SEQ_CST);   // no compiler hoisting
            // preload score partials for all 8 batches (parallel plain loads)
            int s = lane >> 5, f = lane & 31;
#pragma unroll
            for (int bl = 0; bl < 8; ++bl)
                pv[bl] = g_spart[((size_t)(it - 1) * 128 + rg * 16 + bl * 2 + s) * 32 + f];
        }
        // ---------------- selection (replicated, 8 batches) ----------------
        for (int bl = 0; bl < 8; ++bl) {
            int len = s_len[bl];
            int r0 = bl * 2;
            bool active = (it <= len - 2);
            if (!active) {
                if (lane == 0) {
                    s_dl[r0] = 0; s_dr[r0] = 1; s_dd[r0] = -1;
                    s_dl[r0 + 1] = 0; s_dr[r0 + 1] = 1; s_dd[r0 + 1] = -1;
                }
                continue;
            }
            if (it > 0) {
                int s = lane >> 5, f = lane & 31;
                int p = s_np[bl][s];
                float v = (p >= 0) ? pv[bl] : 0.0f;
#pragma unroll
                for (int off = 1; off < 32; off <<= 1) v += __shfl_xor(v, off, 32);
                if (f == 0 && p >= 0) s_score[bl][p] = v / sqrt_h;
                __syncthreads();
            }
            float val = -3.0e38f;
            int idx = lane;
            if (lane < 63 && s_aliv[bl][lane] && s_next[bl][lane] >= 0)
                val = s_score[bl][lane];
#pragma unroll
            for (int off = 1; off < 64; off <<= 1) {
                float ov = __shfl_xor(val, off, 64);
                int oi = __shfl_xor(idx, off, 64);
                if (ov > val || (ov == val && oi < idx)) { val = ov; idx = oi; }
            }
            int a = idx;
            if (a < 0) a = 0;
            if (a > 62) a = 62;
            if (lane == 0) {
                int bn = s_next[bl][a];
                int nn = (bn >= 0) ? s_next[bl][bn] : -1;
                s_next[bl][a] = nn;
                if (nn >= 0) s_prev[bl][nn] = a;
                if (bn >= 0) s_aliv[bl][bn] = 0;
                s_enc[bl][a] = s_prow[bl][a];
                int pL = s_prev[bl][a];
                int pR = (nn >= 0) ? a : -1;
                s_np[bl][0] = pL;
                s_np[bl][1] = pR;
                if (pL >= 0) {
                    s_dl[r0] = s_enc[bl][pL]; s_dr[r0] = s_enc[bl][a];
                    s_dd[r0] = 63 + 2 * it;  s_prow[bl][pL] = 64 + 63 + 2 * it;
                } else { s_dl[r0] = 0; s_dr[r0] = 1; s_dd[r0] = -1; }
                if (pR >= 0) {
                    s_dl[r0 + 1] = s_enc[bl][a]; s_dr[r0 + 1] = s_enc[bl][nn];
                    s_dd[r0 + 1] = 63 + 2 * it + 1; s_prow[bl][a] = 64 + 63 + 2 * it + 1;
                } else { s_dl[r0 + 1] = 0; s_dr[r0 + 1] = 1; s_dd[r0 + 1] = -1; }
            }
        }
        __syncthreads();
        // ---------------- GEMM: 16 pair-rows x 16 cols x 5 gates -----------
        if (it < 62) {
            int b_r = rg * 8 + (l15 >> 1);
            const bf16* lhi = g_uhhi + ((size_t)b_r * UROW + s_dl[l15]) * 512;
            const bf16* llo = g_uhlo + ((size_t)b_r * UROW + s_dl[l15]) * 512;
            const bf16* rhi = g_uhhi + ((size_t)b_r * UROW + s_dr[l15]) * 512;
            const bf16* rlo = g_uhlo + ((size_t)b_r * UROW + s_dr[l15]) * 512;
            f32x4 acc[5] = {};
#pragma unroll 4
            for (int kc = 0; kc < 32; ++kc) {
                int k = kc * 32 + quad * 8;
                int kk = k & 511;
                s16x8 aH = ld8(((kc < 16) ? lhi : rhi) + kk);
                s16x8 aL = ld8(((kc < 16) ? llo : rlo) + kk);
#pragma unroll
                for (int g = 0; g < 5; ++g) {
                    s16x8 bH = ld8(wh + (size_t)g * 512 * 1024 + k);
                    s16x8 bL = ld8(wl + (size_t)g * 512 * 1024 + k);
                    acc[g] = MFMA16(aH, bH, acc[g]);
                    acc[g] = MFMA16(aH, bL, acc[g]);
                    acc[g] = MFMA16(aL, bH, acc[g]);
                }
            }
#pragma unroll
            for (int rr = 0; rr < 4; ++rr) {
                int rowm = quad * 4 + rr;
                int bb = rg * 8 + (rowm >> 1);
                int dest = s_dd[rowm];
                float cl = g_uc[((size_t)bb * UROW + s_dl[rowm]) * 512 + col];
                float cr = g_uc[((size_t)bb * UROW + s_dr[rowm]) * 512 + col];
                float gi = acc[0][rr] + bc[0];
                float fl = acc[1][rr] + bc[1];
                float fr = acc[2][rr] + bc[2];
                float gu = acc[3][rr] + bc[3];
                float go = acc[4][rr] + bc[4];
                float cn = cl * sigf(fl + 1.0f) + cr * sigf(fr + 1.0f) + tanhf(gu) * sigf(gi);
                float hn = sigf(go) * tanhf(cn);
                float sp = hn * qv;
#pragma unroll
                for (int off = 1; off < 16; off <<= 1) sp += __shfl_xor(sp, off, 16);
                if (dest >= 0) {
                    size_t o = ((size_t)bb * UROW + 64 + dest) * 512 + col;
                    bf16 hi = (bf16)hn;
                    sta_bf(&g_uhhi[o], hi);
                    sta_bf(&g_uhlo[o], (bf16)(hn - (float)hi));
                    sta_f(&g_uc[o], cn);
                    g_candh[((size_t)bb * NROW + dest) * 512 + col] = hn;
                    if (l15 == 0)
                        sta_f(&g_spart[((size_t)it * 128 + rg * 16 + rowm) * 32 + fg], sp);
                }
            }
        }
        __syncthreads();
    }
    // ---------------- output: block-local data only ------------------------
    __builtin_amdgcn_s_waitcnt(0);
    for (int bl = 0; bl < 8; ++bl) {
        if ((lane >> 4) != (bl & 3)) continue;
        int b = rg * 8 + bl;
        int e0 = s_enc[bl][0];                    // unified row of root
        float hv, cv;
        if (e0 >= 64) {
            hv = g_candh[((size_t)b * NROW + e0 - 64) * 512 + col];
            cv = g_uc[((size_t)b * UROW + e0) * 512 + col];
        } else {   // unreachable for len>=2, defensive
            size_t o = ((size_t)b * UROW + e0) * 512 + col;
            hv = (float)g_uhhi[o] + (float)g_uhlo[o];
            cv = g_uc[o];
        }
        out[(size_t)b * 512 + col] = hv;
        out[(size_t)(64 * 512) + b * 512 + col] = cv;
    }
}

// ---------------------------------------------------------------------------
extern "C" void kernel_launch(void* const* d_in, const int* in_sizes, int n_in,
                              void* d_out, int out_size, void* d_ws, size_t ws_size,
                              hipStream_t stream) {
    const float* x = (const float*)d_in[0];
    const int* length = (const int*)d_in[1];
    const float* w_word = (const float*)d_in[2];
    const float* b_word = (const float*)d_in[3];
    const float* w_comp = (const float*)d_in[4];
    const float* b_comp = (const float*)d_in[5];
    const float* q = (const float*)d_in[6];
    float* out = (float*)d_out;

    int* barp;
    hipGetSymbolAddress((void**)&barp, HIP_SYMBOL(g_bar));
    hipMemsetAsync(barp, 0, 63 * 128 * sizeof(int), stream);

    hipLaunchKernelGGL(k_prep, dim3(2048), dim3(256), 0, stream, x, w_word, w_comp);
    hipLaunchKernelGGL(k_leaf, dim3(16, 256), dim3(64), 0, stream, b_word);
    hipLaunchKernelGGL(k_cells_init, dim3(32, 63), dim3(64), 0, stream,
                       length, b_comp, q);

    void* args[] = {(void*)&length, (void*)&b_comp, (void*)&q, (void*)&out};
    hipLaunchCooperativeKernel((void*)k_loop_p, dim3(32, 8), dim3(64), args, 0, stream);
}

// Round 10
// 1853.008 us; speedup vs baseline: 1.9443x; 1.4631x over previous
//
#include <hip/hip_runtime.h>

typedef __bf16 bf16;
typedef short s16x8 __attribute__((ext_vector_type(8)));
typedef float f32x4 __attribute__((ext_vector_type(4)));
typedef unsigned long long u64;

#define MFMA16(a, b, c) __builtin_amdgcn_mfma_f32_16x16x32_bf16((a), (b), (c), 0, 0, 0)
#define NROW 187   // cand rows per batch: 63 init + 2/iter
#define UROW 251   // unified rows: 64 leaf + 187 cand

__device__ __forceinline__ float sigf(float x) { return 1.0f / (1.0f + expf(-x)); }
__device__ __forceinline__ s16x8 ld8(const bf16* p) { return *(const s16x8*)p; }

__device__ __forceinline__ unsigned packhl(float v) {
    bf16 h = (bf16)v;
    bf16 l = (bf16)(v - (float)h);
    return (unsigned)__builtin_bit_cast(unsigned short, h) |
           ((unsigned)__builtin_bit_cast(unsigned short, l) << 16);
}
__device__ __forceinline__ u64 lda64(const unsigned* p) {
    return __hip_atomic_load((const u64*)p, __ATOMIC_RELAXED, __HIP_MEMORY_SCOPE_AGENT);
}
__device__ __forceinline__ float ldaf(const float* p) {
    return __hip_atomic_load(p, __ATOMIC_RELAXED, __HIP_MEMORY_SCOPE_AGENT);
}
__device__ __forceinline__ void staf(float* p, float v) {
    __hip_atomic_store(p, v, __ATOMIC_RELAXED, __HIP_MEMORY_SCOPE_AGENT);
}
__device__ __forceinline__ void stau(unsigned* p, unsigned v) {
    __hip_atomic_store(p, v, __ATOMIC_RELAXED, __HIP_MEMORY_SCOPE_AGENT);
}

// ---------------- device-global workspace (fp32 in / fp32 out) -------------
__device__ bf16  g_xhi[64 * 64 * 512], g_xlo[64 * 64 * 512];
__device__ bf16  g_wwhi[1024 * 512], g_wwlo[1024 * 512];
__device__ bf16  g_wchi[2560 * 1024], g_wclo[2560 * 1024];
__device__ bf16  g_hhi[64 * 64 * 512];              // leaf h hi (k_cells_init A)
__device__ bf16  g_hlo[64 * 64 * 512];              // leaf h lo
__device__ unsigned g_uhl[(size_t)64 * UROW * 512]; // unified h packed (hi|lo<<16)
__device__ float g_uc[(size_t)64 * UROW * 512];     // unified c fp32
__device__ float g_candh[(size_t)64 * NROW * 512];  // cand h fp32 (self-read only)
__device__ float g_spinit[64 * 63 * 32];
__device__ float g_spart[2 * 128 * 32];             // [parity][rg*16+row][fg]
__device__ int   g_bar[63 * 128];                   // [it][rg*16]

// ---------------- prep: all three fp32 -> bf16 hi/lo splits ----------------
__global__ __launch_bounds__(256) void k_prep(const float* __restrict__ x,
                                              const float* __restrict__ ww,
                                              const float* __restrict__ wc) {
    const int NX = 64 * 64 * 512, NW = 1024 * 512, NC = 2560 * 1024;
    int stride = gridDim.x * 256, i0 = blockIdx.x * 256 + threadIdx.x;
    for (int i = i0; i < NX; i += stride) {
        float v = x[i];
        bf16 h = (bf16)v;
        g_xhi[i] = h;
        g_xlo[i] = (bf16)(v - (float)h);
    }
    for (int i = i0; i < NW; i += stride) {
        float v = ww[i];
        bf16 h = (bf16)v;
        g_wwhi[i] = h;
        g_wwlo[i] = (bf16)(v - (float)h);
    }
    for (int i = i0; i < NC; i += stride) {
        float v = wc[i];
        bf16 h = (bf16)v;
        g_wchi[i] = h;
        g_wclo[i] = (bf16)(v - (float)h);
    }
}

// ---------------------------------------------------------------------------
// K0: leaf projection (M=4096, N=1024, K=512), 3-pass hi/lo MFMA.
// Layouts (m89/m120): A[m=l15][k=quad*8+j], B[k][n=l15], D row=quad*4+reg.
// ---------------------------------------------------------------------------
__global__ __launch_bounds__(64) void k_leaf(const float* __restrict__ b_word) {
    int cg = blockIdx.x, rg = blockIdx.y;
    int lane = threadIdx.x, l15 = lane & 15, quad = lane >> 4;
    const bf16* axh = g_xhi + (size_t)(rg * 16 + l15) * 512;
    const bf16* axl = g_xlo + (size_t)(rg * 16 + l15) * 512;
    const bf16* bwh = g_wwhi + (size_t)(cg * 64 + l15) * 512;
    const bf16* bwl = g_wwlo + (size_t)(cg * 64 + l15) * 512;
    f32x4 acc[4] = {};
    for (int kc = 0; kc < 16; ++kc) {
        int k = kc * 32 + quad * 8;
        s16x8 aH = ld8(axh + k), aL = ld8(axl + k);
#pragma unroll
        for (int t = 0; t < 4; ++t) {
            s16x8 bH = ld8(bwh + (size_t)t * 16 * 512 + k);
            s16x8 bL = ld8(bwl + (size_t)t * 16 * 512 + k);
            acc[t] = MFMA16(aH, bH, acc[t]);
            acc[t] = MFMA16(aH, bL, acc[t]);
            acc[t] = MFMA16(aL, bH, acc[t]);
        }
    }
#pragma unroll
    for (int t = 0; t < 4; ++t) {
        int col = cg * 64 + t * 16 + l15;
        float bw = b_word[col];
#pragma unroll
        for (int r = 0; r < 4; ++r) {
            int m = rg * 16 + quad * 4 + r;
            int bb = m >> 6, sl = m & 63;
            float v = acc[t][r] + bw;
            if (col < 512) {
                bf16 hi = (bf16)v;
                g_hhi[(size_t)m * 512 + col] = hi;
                g_hlo[(size_t)m * 512 + col] = (bf16)(v - (float)hi);
                g_uhl[((size_t)bb * UROW + sl) * 512 + col] = packhl(v);
            } else {
                g_uc[((size_t)bb * UROW + sl) * 512 + (col - 512)] = v;
            }
        }
    }
}

// ---------------------------------------------------------------------------
// K1: initial candidates, all pairs (b,j) -> unified rows 64..126.
// ---------------------------------------------------------------------------
__global__ __launch_bounds__(64) void k_cells_init(const int* __restrict__ length,
                                                   const float* __restrict__ b_comp,
                                                   const float* __restrict__ q) {
    int fg = blockIdx.x;            // 0..31
    int rg = blockIdx.y;            // 0..62
    int lane = threadIdx.x, l15 = lane & 15, quad = lane >> 4;

    const bf16 *ahi[4], *alo[4];
#pragma unroll
    for (int t = 0; t < 4; ++t) {
        int r = rg * 64 + t * 16 + l15;      // pair row 0..4031
        int b = r / 63, j = r - b * 63;
        ahi[t] = g_hhi + (size_t)(b * 64 + j) * 512;
        alo[t] = g_hlo + (size_t)(b * 64 + j) * 512;
    }
    const bf16* wh = g_wchi + (size_t)(fg * 16 + l15) * 1024;
    const bf16* wl = g_wclo + (size_t)(fg * 16 + l15) * 1024;
    f32x4 acc[4][5] = {};
    for (int kc = 0; kc < 32; ++kc) {
        int k = kc * 32 + quad * 8;
        int kk = k & 511;
        size_t sh = (k < 512) ? 0 : 512;     // row j vs j+1 (contiguous rows)
        s16x8 aH[4], aL[4];
#pragma unroll
        for (int t = 0; t < 4; ++t) {
            aH[t] = ld8(ahi[t] + sh + kk);
            aL[t] = ld8(alo[t] + sh + kk);
        }
#pragma unroll
        for (int g = 0; g < 5; ++g) {
            s16x8 bH = ld8(wh + (size_t)g * 512 * 1024 + k);
            s16x8 bL = ld8(wl + (size_t)g * 512 * 1024 + k);
#pragma unroll
            for (int t = 0; t < 4; ++t) {
                acc[t][g] = MFMA16(aH[t], bH, acc[t][g]);
                acc[t][g] = MFMA16(aH[t], bL, acc[t][g]);
                acc[t][g] = MFMA16(aL[t], bH, acc[t][g]);
            }
        }
    }
    int col = fg * 16 + l15;
    float bc[5];
#pragma unroll
    for (int g = 0; g < 5; ++g) bc[g] = b_comp[g * 512 + col];
    float qv = q[col];
#pragma unroll
    for (int t = 0; t < 4; ++t) {
#pragma unroll
        for (int rr = 0; rr < 4; ++rr) {
            int R = rg * 64 + t * 16 + quad * 4 + rr;
            int B_ = R / 63, J = R - B_ * 63;
            bool act = (J <= length[B_] - 2);
            float gi = acc[t][0][rr] + bc[0];
            float fl = acc[t][1][rr] + bc[1];
            float fr = acc[t][2][rr] + bc[2];
            float gu = acc[t][3][rr] + bc[3];
            float go = acc[t][4][rr] + bc[4];
            float cl = g_uc[((size_t)B_ * UROW + J) * 512 + col];
            float cr = g_uc[((size_t)B_ * UROW + J + 1) * 512 + col];
            float cn = cl * sigf(fl + 1.0f) + cr * sigf(fr + 1.0f) + tanhf(gu) * sigf(gi);
            float hn = sigf(go) * tanhf(cn);
            float sp = hn * qv;
#pragma unroll
            for (int off = 1; off < 16; off <<= 1) sp += __shfl_xor(sp, off, 16);
            if (act) {
                size_t o = ((size_t)B_ * UROW + 64 + J) * 512 + col;
                g_uhl[o] = packhl(hn);
                g_uc[o] = cn;
                g_candh[((size_t)B_ * NROW + J) * 512 + col] = hn;
                if (l15 == 0) g_spinit[(size_t)R * 32 + fg] = sp;
            }
        }
    }
}

// ---------------------------------------------------------------------------
// K_loop_p: ONE persistent kernel, 63 iterations. grid (32 fg, 8 rg) x 256.
// 4 waves/block: K split 4 ways (wave w: kc in [8w,8w+8)), LDS-reduced.
// Selection: wave w owns batches {2w, 2w+1} (disjoint LDS state, no inner
// syncthreads — wave-coherent LDS). Epilogue + sc1 stores: wave0 only.
// Transport = R8 (atomic loads/stores, absmax-stable); barrier = R8.
// ---------------------------------------------------------------------------
__global__ __launch_bounds__(256) void k_loop_p(const int* __restrict__ length,
                                                const float* __restrict__ b_comp,
                                                const float* __restrict__ q,
                                                float* __restrict__ out) {
    int fg = blockIdx.x, rg = blockIdx.y;
    int tid = threadIdx.x;
    int wv = tid >> 6, lane = tid & 63;
    int l15 = lane & 15, quad = lane >> 4;
    const float sqrt_h = 22.627416997969522f;

    __shared__ int s_next[8][64], s_prev[8][64], s_aliv[8][64];
    __shared__ int s_enc[8][64];    // slot -> enc (<64 leaf, 64+candrow)
    __shared__ int s_prow[8][64];   // left-slot -> cand row of its current pair
    __shared__ float s_score[8][64];
    __shared__ int s_np[8][2];
    __shared__ int s_dl[16], s_dr[16], s_dd[16];
    __shared__ int s_len[8];
    __shared__ float s_red[192][20]; // waves 1-3 partial acc (5 tiles x 4)

    // ---- init: each wave builds its own 2 batches ----
    for (int bl = wv * 2; bl < wv * 2 + 2; ++bl) {
        int b = rg * 8 + bl;
        int len = length[b];
        if (lane == 0) { s_len[bl] = len; s_np[bl][0] = -1; s_np[bl][1] = -1; }
        s_next[bl][lane] = (lane < len - 1) ? lane + 1 : -1;
        s_prev[bl][lane] = (lane > 0 && lane < len) ? lane - 1 : -1;
        s_aliv[bl][lane] = (lane < len) ? 1 : 0;
        s_enc[bl][lane] = lane;
        s_prow[bl][lane] = lane;
        float sc = -3.0e38f;
        if (lane < 63 && lane <= len - 2) {
            float s = 0.0f;
            for (int f = 0; f < 32; ++f) s += g_spinit[(size_t)(b * 63 + lane) * 32 + f];
            sc = s / sqrt_h;
        }
        s_score[bl][lane] = sc;
    }
    __syncthreads();

    int col = fg * 16 + l15;
    float bc[5];
#pragma unroll
    for (int g = 0; g < 5; ++g) bc[g] = b_comp[g * 512 + col];
    float qv = q[col];
    const bf16* wh = g_wchi + (size_t)col * 1024;
    const bf16* wl = g_wclo + (size_t)col * 1024;

    for (int it = 0; it < 63; ++it) {
        if (it > 0) {
            __builtin_amdgcn_s_waitcnt(0);   // drain own sc1 stores (wave0)
            __syncthreads();
            if (tid == 0) {
                int* bp = &g_bar[it * 128 + rg * 16];
                __hip_atomic_fetch_add(bp, 1, __ATOMIC_RELAXED, __HIP_MEMORY_SCOPE_AGENT);
                while (__hip_atomic_load(bp, __ATOMIC_RELAXED, __HIP_MEMORY_SCOPE_AGENT) < 32)
                    __builtin_amdgcn_s_sleep(2);
            }
            __syncthreads();
            __atomic_signal_fence(__ATOMIC_SEQ_CST);
        }
        // ------------- selection: wave w owns batches {2w, 2w+1} -----------
        for (int bl = wv * 2; bl < wv * 2 + 2; ++bl) {
            int len = s_len[bl];
            int r0 = bl * 2;
            bool active = (it <= len - 2);
            if (!active) {
                if (lane == 0) {
                    s_dl[r0] = 0; s_dr[r0] = 1; s_dd[r0] = -1;
                    s_dl[r0 + 1] = 0; s_dr[r0 + 1] = 1; s_dd[r0 + 1] = -1;
                }
                continue;
            }
            if (it > 0) {
                int s = lane >> 5, f = lane & 31;
                int p = s_np[bl][s];
                float v = (p >= 0)
                    ? ldaf(&g_spart[(((it - 1) & 1) * 128 + rg * 16 + r0 + s) * 32 + f])
                    : 0.0f;
#pragma unroll
                for (int off = 1; off < 32; off <<= 1) v += __shfl_xor(v, off, 32);
                if (f == 0 && p >= 0) s_score[bl][p] = v / sqrt_h;
            }
            float val = -3.0e38f;
            int idx = lane;
            if (lane < 63 && s_aliv[bl][lane] && s_next[bl][lane] >= 0)
                val = s_score[bl][lane];
#pragma unroll
            for (int off = 1; off < 64; off <<= 1) {
                float ov = __shfl_xor(val, off, 64);
                int oi = __shfl_xor(idx, off, 64);
                if (ov > val || (ov == val && oi < idx)) { val = ov; idx = oi; }
            }
            int a = idx;
            if (a < 0) a = 0;
            if (a > 62) a = 62;
            if (lane == 0) {
                int bn = s_next[bl][a];
                int nn = (bn >= 0) ? s_next[bl][bn] : -1;
                s_next[bl][a] = nn;
                if (nn >= 0) s_prev[bl][nn] = a;
                if (bn >= 0) s_aliv[bl][bn] = 0;
                s_enc[bl][a] = 64 + s_prow[bl][a];
                int pL = s_prev[bl][a];
                int pR = (nn >= 0) ? a : -1;
                s_np[bl][0] = pL;
                s_np[bl][1] = pR;
                if (pL >= 0) {
                    s_dl[r0] = s_enc[bl][pL]; s_dr[r0] = s_enc[bl][a];
                    s_dd[r0] = 63 + 2 * it;  s_prow[bl][pL] = 63 + 2 * it;
                } else { s_dl[r0] = 0; s_dr[r0] = 1; s_dd[r0] = -1; }
                if (pR >= 0) {
                    s_dl[r0 + 1] = s_enc[bl][a]; s_dr[r0 + 1] = s_enc[bl][nn];
                    s_dd[r0 + 1] = 63 + 2 * it + 1; s_prow[bl][a] = 63 + 2 * it + 1;
                } else { s_dl[r0 + 1] = 0; s_dr[r0 + 1] = 1; s_dd[r0 + 1] = -1; }
            }
        }
        __syncthreads();
        // ------------- GEMM: K split across 4 waves ------------------------
        if (it < 62) {
            int b_r = rg * 8 + (l15 >> 1);
            const unsigned* la = g_uhl + ((size_t)b_r * UROW + s_dl[l15]) * 512;
            const unsigned* ra = g_uhl + ((size_t)b_r * UROW + s_dr[l15]) * 512;
            f32x4 acc[5] = {};
            for (int i = 0; i < 8; ++i) {
                int kc = wv * 8 + i;
                int k = kc * 32 + quad * 8;
                int kk = k & 511;
                const unsigned* ap = ((k < 512) ? la : ra) + kk;
                u64 u0 = lda64(ap), u1 = lda64(ap + 2);
                u64 u2 = lda64(ap + 4), u3 = lda64(ap + 6);
                s16x8 aH, aL;
                aH[0] = (short)u0; aL[0] = (short)(u0 >> 16);
                aH[1] = (short)(u0 >> 32); aL[1] = (short)(u0 >> 48);
                aH[2] = (short)u1; aL[2] = (short)(u1 >> 16);
                aH[3] = (short)(u1 >> 32); aL[3] = (short)(u1 >> 48);
                aH[4] = (short)u2; aL[4] = (short)(u2 >> 16);
                aH[5] = (short)(u2 >> 32); aL[5] = (short)(u2 >> 48);
                aH[6] = (short)u3; aL[6] = (short)(u3 >> 16);
                aH[7] = (short)(u3 >> 32); aL[7] = (short)(u3 >> 48);
#pragma unroll
                for (int g = 0; g < 5; ++g) {
                    s16x8 bH = ld8(wh + (size_t)g * 512 * 1024 + k);
                    s16x8 bL = ld8(wl + (size_t)g * 512 * 1024 + k);
                    acc[g] = MFMA16(aH, bH, acc[g]);
                    acc[g] = MFMA16(aH, bL, acc[g]);
                    acc[g] = MFMA16(aL, bH, acc[g]);
                }
            }
            if (wv > 0) {
#pragma unroll
                for (int g = 0; g < 5; ++g)
#pragma unroll
                    for (int rr = 0; rr < 4; ++rr)
                        s_red[(wv - 1) * 64 + lane][g * 4 + rr] = acc[g][rr];
            }
            __syncthreads();
            if (wv == 0) {
                // deterministic reduction: w0 + w1 + w2 + w3
#pragma unroll
                for (int g = 0; g < 5; ++g)
#pragma unroll
                    for (int rr = 0; rr < 4; ++rr)
                        acc[g][rr] = ((acc[g][rr] + s_red[lane][g * 4 + rr])
                                      + s_red[64 + lane][g * 4 + rr])
                                     + s_red[128 + lane][g * 4 + rr];
                float cl[4], cr[4];
#pragma unroll
                for (int rr = 0; rr < 4; ++rr) {
                    int rowm = quad * 4 + rr;
                    int bb = rg * 8 + (rowm >> 1);
                    cl[rr] = ldaf(&g_uc[((size_t)bb * UROW + s_dl[rowm]) * 512 + col]);
                    cr[rr] = ldaf(&g_uc[((size_t)bb * UROW + s_dr[rowm]) * 512 + col]);
                }
#pragma unroll
                for (int rr = 0; rr < 4; ++rr) {
                    int rowm = quad * 4 + rr;
                    int bb = rg * 8 + (rowm >> 1);
                    int dest = s_dd[rowm];
                    float gi = acc[0][rr] + bc[0];
                    float fl = acc[1][rr] + bc[1];
                    float fr = acc[2][rr] + bc[2];
                    float gu = acc[3][rr] + bc[3];
                    float go = acc[4][rr] + bc[4];
                    float cn = cl[rr] * sigf(fl + 1.0f) + cr[rr] * sigf(fr + 1.0f)
                               + tanhf(gu) * sigf(gi);
                    float hn = sigf(go) * tanhf(cn);
                    float sp = hn * qv;
#pragma unroll
                    for (int off = 1; off < 16; off <<= 1) sp += __shfl_xor(sp, off, 16);
                    if (dest >= 0) {
                        size_t o = ((size_t)bb * UROW + 64 + dest) * 512 + col;
                        stau(&g_uhl[o], packhl(hn));
                        staf(&g_uc[o], cn);
                        g_candh[((size_t)bb * NROW + dest) * 512 + col] = hn;
                        if (l15 == 0)
                            staf(&g_spart[((it & 1) * 128 + rg * 16 + rowm) * 32 + fg], sp);
                    }
                }
            }
        }
        __syncthreads();
    }
    // ---------------- output: wave0, block-owned cols ----------------------
    if (wv == 0) {
        __builtin_amdgcn_s_waitcnt(0);
        for (int bl = 0; bl < 8; ++bl) {
            if ((lane >> 4) != (bl & 3)) continue;
            int b = rg * 8 + bl;
            int e0 = s_enc[bl][0];
            float hv, cv;
            if (e0 >= 64) {
                hv = g_candh[((size_t)b * NROW + e0 - 64) * 512 + col];
                cv = ldaf(&g_uc[((size_t)b * UROW + e0) * 512 + col]);
            } else {   // unreachable for len>=2, defensive
                unsigned u = g_uhl[((size_t)b * UROW + e0) * 512 + col];
                bf16 h0 = __builtin_bit_cast(bf16, (unsigned short)(u & 0xffff));
                bf16 l0 = __builtin_bit_cast(bf16, (unsigned short)(u >> 16));
                hv = (float)h0 + (float)l0;
                cv = ldaf(&g_uc[((size_t)b * UROW + e0) * 512 + col]);
            }
            out[(size_t)b * 512 + col] = hv;
            out[(size_t)(64 * 512) + b * 512 + col] = cv;
        }
    }
}

// ---------------------------------------------------------------------------
extern "C" void kernel_launch(void* const* d_in, const int* in_sizes, int n_in,
                              void* d_out, int out_size, void* d_ws, size_t ws_size,
                              hipStream_t stream) {
    const float* x = (const float*)d_in[0];
    const int* length = (const int*)d_in[1];
    const float* w_word = (const float*)d_in[2];
    const float* b_word = (const float*)d_in[3];
    const float* w_comp = (const float*)d_in[4];
    const float* b_comp = (const float*)d_in[5];
    const float* q = (const float*)d_in[6];
    float* out = (float*)d_out;

    int* barp;
    hipGetSymbolAddress((void**)&barp, HIP_SYMBOL(g_bar));
    hipMemsetAsync(barp, 0, 63 * 128 * sizeof(int), stream);

    hipLaunchKernelGGL(k_prep, dim3(2048), dim3(256), 0, stream, x, w_word, w_comp);
    hipLaunchKernelGGL(k_leaf, dim3(16, 256), dim3(64), 0, stream, b_word);
    hipLaunchKernelGGL(k_cells_init, dim3(32, 63), dim3(64), 0, stream,
                       length, b_comp, q);

    void* args[] = {(void*)&length, (void*)&b_comp, (void*)&q, (void*)&out};
    hipLaunchCooperativeKernel((void*)k_loop_p, dim3(32, 8), dim3(256), args, 0, stream);
}